// Round 7
// baseline (7346.845 us; speedup 1.0000x reference)
//
#include <hip/hip_runtime.h>

typedef __attribute__((ext_vector_type(8))) short bf16x8;
typedef __attribute__((ext_vector_type(4))) float f32x4;

#define T_LEN 256
#define NROW  8192
// pack offsets (short units)
#define OFF_W1   0
#define OFF_W2   8192
#define OFF_W31  24576
#define OFF_W3   40960
#define OFF_WU1  49152
#define OFF_WR1  65536
#define OFF_WN1  81920
#define OFF_WU2  98304
#define OFF_WR2  106496
#define OFF_WN2  114688
#define OFF_B3W1 131072   // f32[128] appended after bf16 packs
#define PREP_TOT 131200

// workspace byte offsets (pack occupies [0, 262400))
#define XMK_OFF  524288u                    // float2[256][8192] = 16 MiB
#define DTS_OFF  (XMK_OFF + NROW*T_LEN*8u)  // float[256]

// LDS layout (short units)
#define HA_O   0      // [16][128]
#define HB_O   2048   // [16][128]
#define SGH_O  4096   // [16][128]
#define SGL_O  6144   // [16][128]
#define ST_O   8192   // [16][64] st-mean bf16
#define LDS_SHORTS 9216

__device__ __forceinline__ unsigned short bf16r(float f){
  unsigned int x = __builtin_bit_cast(unsigned int, f);
  unsigned int r = (x + 0x7FFFu + ((x >> 16) & 1u)) >> 16;
  return (unsigned short)r;
}
__device__ __forceinline__ float bf16tof(unsigned short u){
  unsigned int v = ((unsigned int)u) << 16;
  return __builtin_bit_cast(float, v);
}
__device__ __forceinline__ float fast_tanh(float x){
  float e = __builtin_amdgcn_exp2f(x * 2.885390081777927f);   // exp(2x)
  return 1.0f - 2.0f * __builtin_amdgcn_rcpf(1.0f + e);
}
__device__ __forceinline__ float fast_sigmoid(float x){
  float e = __builtin_amdgcn_exp2f(x * -1.4426950408889634f); // exp(-x)
  return __builtin_amdgcn_rcpf(1.0f + e);
}
__device__ __forceinline__ f32x4 mfma16(bf16x8 a, bf16x8 b, f32x4 c){
  return __builtin_amdgcn_mfma_f32_16x16x32_bf16(a, b, c, 0, 0, 0);
}
__device__ __forceinline__ bf16x8 load_bfrag(const unsigned short* p, int blk, int lane){
  return *reinterpret_cast<const bf16x8*>(p + ((blk << 6) + lane) * 8);
}
__device__ __forceinline__ bf16x8 ldsA(const unsigned short* LDSU, int idx){
  return *reinterpret_cast<const bf16x8*>(LDSU + idx);
}

// Pack weights to bf16 MFMA B-fragment order; compute W31=W3@W1, b3W1=b3@W1.
__global__ void prep_pack(const float* __restrict__ W1, const float* __restrict__ W2,
                          const float* __restrict__ W3, const float* __restrict__ Wu1,
                          const float* __restrict__ Wr1, const float* __restrict__ Wn1,
                          const float* __restrict__ Wu2, const float* __restrict__ Wr2,
                          const float* __restrict__ Wn2, const float* __restrict__ b3,
                          unsigned short* __restrict__ pack)
{
  int e = blockIdx.x * blockDim.x + threadIdx.x;
  if (e >= PREP_TOT) return;
  if (e >= OFF_B3W1){
    int j = e - OFF_B3W1;           // 0..127
    float s = 0.0f;
    for (int mm = 0; mm < 64; ++mm) s += b3[mm] * W1[mm * 128 + j];
    ((float*)(pack + OFF_B3W1))[j] = s;
    return;
  }
  const int offs[11] = {0, 8192, 24576, 40960, 49152, 65536, 81920, 98304, 106496, 114688, 131072};
  const int Ks[10] = {64,128,128,128,128,128,128,128,128,128};
  const int Ns[10] = {128,128,128,64,128,128,128,64,64,128};
  int m = 0;
  while (e >= offs[m + 1]) ++m;
  int el = e - offs[m];
  int j = el & 7, lane = (el >> 3) & 63, blk = el >> 9;
  int ksteps = Ks[m] >> 5;
  int ks = blk % ksteps, nt = blk / ksteps;
  int k = ks * 32 + ((lane >> 4) << 3) + j;
  int n = nt * 16 + (lane & 15);
  float v;
  if (m == 2){ // W31[k][n] = sum_mm W3[k][mm] * W1[mm][n]
    float s = 0.0f;
    for (int mm = 0; mm < 64; ++mm) s += W3[k * 64 + mm] * W1[mm * 128 + n];
    v = s;
  } else {
    const float* srcs[10] = {W1, W2, nullptr, W3, Wu1, Wr1, Wn1, Wu2, Wr2, Wn2};
    v = srcs[m][k * Ns[m] + n];
  }
  pack[e] = bf16r(v);
}

// Transpose x/mask to step-major float2 and precompute dt per step.
__global__ void prep_xmk(const float* __restrict__ b, const float* __restrict__ m,
                         float2* __restrict__ xmk, float* __restrict__ dts)
{
  int e = blockIdx.x * blockDim.x + threadIdx.x;
  if (e < NROW * T_LEN){
    int s = e >> 13, row = e & (NROW - 1);
    int tj = T_LEN - 1 - s;
    xmk[e] = make_float2(b[row * 512 + tj * 2 + 1], m[row * 256 + tj]);
  }
  if (e < T_LEN){
    int tj = T_LEN - 1 - e;
    float t1 = b[2 * tj];
    float t0 = (e == 0) ? 5.0f : b[2 * tj + 2];
    dts[e] = t1 - t0;
  }
}

__global__ __launch_bounds__(256, 4) void ode_rnn_main(
  const float* __restrict__ b1, const float* __restrict__ b2, const float* __restrict__ b3,
  const float* __restrict__ bu1, const float* __restrict__ bu2,
  const float* __restrict__ br1, const float* __restrict__ br2,
  const float* __restrict__ bn1, const float* __restrict__ bn2,
  const float* __restrict__ Wu1f, const float* __restrict__ Wr1f, const float* __restrict__ Wn1f,
  const unsigned short* __restrict__ pack, const float2* __restrict__ xmk,
  const float* __restrict__ dts, float* __restrict__ out)
{
  __shared__ __align__(16) unsigned short LDSU[LDS_SHORTS];
  const int tid = threadIdx.x, w = tid >> 6, lane = tid & 63;
  const int arow = lane & 15, g = lane >> 4, rb = g << 2;
  const int c1280 = (w << 5) + arow;   // tile 2w column; tile 2w+1 column = c1280+16
  const int c64   = (w << 4) + arow;
  const int rowBase = blockIdx.x * 16;

  // precomputed LDS indices (short units)
  int a128[4], a64v[2], wrA[4], wrm[4], wr64[4];
#pragma unroll
  for (int ks = 0; ks < 4; ++ks) a128[ks] = arow*128 + ((32*ks + 8*g) ^ (arow << 3));
#pragma unroll
  for (int ks = 0; ks < 2; ++ks) a64v[ks] = arow*64 + ((32*ks + 8*g) ^ ((arow & 7) << 3));
#pragma unroll
  for (int i = 0; i < 4; ++i){
    int r = rb + i;
    wrA[i]  = r*128 + (c1280 ^ (r << 3));           // tile 2w; tile 2w+1 = ^16
    wrm[i]  = r*128 + (c64 ^ (r << 3));             // mean col; std col = ^64
    wr64[i] = r*64  + (c64 ^ ((r & 7) << 3));
  }

  // persistent registers: W1 fragments only (2 tiles x 2 ksteps)
  bf16x8 w1f[2][2];
#pragma unroll
  for (int t = 0; t < 2; ++t)
#pragma unroll
    for (int ks = 0; ks < 2; ++ks) w1f[t][ks] = load_bfrag(pack + OFF_W1, (2*w + t)*2 + ks, lane);

  const float* b3w1p = (const float*)(pack + OFF_B3W1);
  float b1c[2], b2c[2], b3w1c[2], bu1c[2], br1c[2], bn1c[2], wu1L[2], wr1L[2], wn1L[2];
#pragma unroll
  for (int t = 0; t < 2; ++t){
    int c = c1280 + 16*t;
    b1c[t] = b1[c]; b2c[t] = b2[c]; b3w1c[t] = b3w1p[c];
    bu1c[t] = bu1[c]; br1c[t] = br1[c]; bn1c[t] = bn1[c];
    wu1L[t] = Wu1f[16384 + c]; wr1L[t] = Wr1f[16384 + c]; wn1L[t] = Wn1f[16384 + c];
  }
  const float b3c = b3[c64], bu2c = bu2[c64], br2c = br2[c64];
  const float bn2cm = bn2[c64], bn2cs = bn2[64 + c64];

  // zero st-mean buffer
  ((unsigned long long*)(LDSU + ST_O))[tid] = 0ULL;
  __syncthreads();

  f32x4 stm = {0.f,0.f,0.f,0.f}, sts = {0.f,0.f,0.f,0.f};
  f32x4 yf  = {0.f,0.f,0.f,0.f}, u = {0.f,0.f,0.f,0.f};

#pragma unroll 1
  for (int s = 0; s < T_LEN; ++s){
    const float hh = dts[s];
    const float2* xp = xmk + (size_t)s * NROW + rowBase + rb;
    f32x4 xr, mk;
#pragma unroll
    for (int i = 0; i < 4; ++i){ float2 v = xp[i]; xr[i] = v.x; mk[i] = v.y; }

    f32x4 R[2], Hsum[2];

    // ---- p0: h1 stage1 from st-mean (K=64) ----
#pragma unroll
    for (int t = 0; t < 2; ++t){
      f32x4 acc = (f32x4){b1c[t], b1c[t], b1c[t], b1c[t]};
      acc = mfma16(ldsA(LDSU, ST_O + a64v[0]), w1f[t][0], acc);
      acc = mfma16(ldsA(LDSU, ST_O + a64v[1]), w1f[t][1], acc);
      R[t] = acc;
#pragma unroll
      for (int i = 0; i < 4; ++i) LDSU[HA_O + (wrA[i] ^ (t << 4))] = bf16r(fast_tanh(acc[i]));
    }
    __syncthreads();
    // ---- 3x { h2 stage | h1 stage } ----
#pragma unroll
    for (int hs = 0; hs < 3; ++hs){
      const float wgt = (hs == 0) ? 1.0f : 2.0f;
      const float scn = (hs == 2) ? hh : 0.5f * hh;
#pragma unroll
      for (int t = 0; t < 2; ++t){
        bf16x8 bw[4];
#pragma unroll
        for (int ks = 0; ks < 4; ++ks) bw[ks] = load_bfrag(pack + OFF_W2, (2*w + t)*4 + ks, lane);
        f32x4 acc = (f32x4){b2c[t], b2c[t], b2c[t], b2c[t]};
#pragma unroll
        for (int ks = 0; ks < 4; ++ks) acc = mfma16(ldsA(LDSU, HA_O + a128[ks]), bw[ks], acc);
        f32x4 h;
#pragma unroll
        for (int i = 0; i < 4; ++i) h[i] = fast_tanh(acc[i]);
        if (hs == 0) Hsum[t] = h;
        else {
#pragma unroll
          for (int i = 0; i < 4; ++i) Hsum[t][i] += wgt * h[i];
        }
#pragma unroll
        for (int i = 0; i < 4; ++i) LDSU[SGH_O + (wrA[i] ^ (t << 4))] = bf16r(h[i] * scn);
      }
      __syncthreads();
      const float ac = (hs == 2) ? hh : 0.5f * hh;
#pragma unroll
      for (int t = 0; t < 2; ++t){
        bf16x8 bw[4];
#pragma unroll
        for (int ks = 0; ks < 4; ++ks) bw[ks] = load_bfrag(pack + OFF_W31, (2*w + t)*4 + ks, lane);
        f32x4 acc;
#pragma unroll
        for (int i = 0; i < 4; ++i) acc[i] = R[t][i] + ac * b3w1c[t];
#pragma unroll
        for (int ks = 0; ks < 4; ++ks) acc = mfma16(ldsA(LDSU, SGH_O + a128[ks]), bw[ks], acc);
#pragma unroll
        for (int i = 0; i < 4; ++i) LDSU[HA_O + (wrA[i] ^ (t << 4))] = bf16r(fast_tanh(acc[i]));
      }
      __syncthreads();
    }
    // ---- p7: h2 stage4, Gsum hi/lo -> HB/SGH ----
    {
      const float sc6 = hh * (1.0f / 6.0f);
#pragma unroll
      for (int t = 0; t < 2; ++t){
        bf16x8 bw[4];
#pragma unroll
        for (int ks = 0; ks < 4; ++ks) bw[ks] = load_bfrag(pack + OFF_W2, (2*w + t)*4 + ks, lane);
        f32x4 acc = (f32x4){b2c[t], b2c[t], b2c[t], b2c[t]};
#pragma unroll
        for (int ks = 0; ks < 4; ++ks) acc = mfma16(ldsA(LDSU, HA_O + a128[ks]), bw[ks], acc);
#pragma unroll
        for (int i = 0; i < 4; ++i){
          float gv = (Hsum[t][i] + fast_tanh(acc[i])) * sc6;
          unsigned short hi = bf16r(gv);
          LDSU[HB_O  + (wrA[i] ^ (t << 4))] = hi;
          LDSU[SGH_O + (wrA[i] ^ (t << 4))] = bf16r(gv - bf16tof(hi));
        }
      }
    }
    __syncthreads();
    // ---- Y: mean_ode = st + Gsum@W3 + hh*b3; write state hi/lo -> HA/SGL ----
    {
      bf16x8 w3f[4];
#pragma unroll
      for (int ks = 0; ks < 4; ++ks) w3f[ks] = load_bfrag(pack + OFF_W3, 4*w + ks, lane);
      f32x4 acc = {0.f,0.f,0.f,0.f};
#pragma unroll
      for (int ks = 0; ks < 4; ++ks) acc = mfma16(ldsA(LDSU, HB_O  + a128[ks]), w3f[ks], acc);
#pragma unroll
      for (int ks = 0; ks < 4; ++ks) acc = mfma16(ldsA(LDSU, SGH_O + a128[ks]), w3f[ks], acc);
#pragma unroll
      for (int i = 0; i < 4; ++i) yf[i] = stm[i] + acc[i] + hh * b3c;
#pragma unroll
      for (int i = 0; i < 4; ++i){
        unsigned short hi = bf16r(yf[i]);
        LDSU[HA_O  + wrm[i]] = hi;
        LDSU[SGL_O + wrm[i]] = bf16r(yf[i] - bf16tof(hi));
        unsigned short hs2 = bf16r(sts[i]);
        LDSU[HA_O  + (wrm[i] ^ 64)] = hs2;
        LDSU[SGL_O + (wrm[i] ^ 64)] = bf16r(sts[i] - bf16tof(hs2));
      }
    }
    __syncthreads();
    // ---- g1: u & r first layers (read HA/SGL, write HB(u)/SGH(r)) ----
#pragma unroll
    for (int t = 0; t < 2; ++t){
      bf16x8 bu_[4], br_[4];
#pragma unroll
      for (int ks = 0; ks < 4; ++ks){
        bu_[ks] = load_bfrag(pack + OFF_WU1, (2*w + t)*4 + ks, lane);
        br_[ks] = load_bfrag(pack + OFF_WR1, (2*w + t)*4 + ks, lane);
      }
      f32x4 au = {0.f,0.f,0.f,0.f}, ar = {0.f,0.f,0.f,0.f};
#pragma unroll
      for (int ks = 0; ks < 4; ++ks){
        bf16x8 ah = ldsA(LDSU, HA_O  + a128[ks]);
        bf16x8 al = ldsA(LDSU, SGL_O + a128[ks]);
        au = mfma16(al, bu_[ks], au); au = mfma16(ah, bu_[ks], au);
        ar = mfma16(al, br_[ks], ar); ar = mfma16(ah, br_[ks], ar);
      }
#pragma unroll
      for (int i = 0; i < 4; ++i){
        LDSU[HB_O  + (wrA[i] ^ (t << 4))] = bf16r(fast_tanh(au[i] + bu1c[t] + xr[i] * wu1L[t]));
        LDSU[SGH_O + (wrA[i] ^ (t << 4))] = bf16r(fast_tanh(ar[i] + br1c[t] + xr[i] * wr1L[t]));
      }
    }
    __syncthreads();
    // ---- g2+g3: second layers (u from HB, r from SGH) + gated state -> HA/SGL ----
    {
      bf16x8 wu2[4], wr2[4];
#pragma unroll
      for (int ks = 0; ks < 4; ++ks){
        wu2[ks] = load_bfrag(pack + OFF_WU2, 4*w + ks, lane);
        wr2[ks] = load_bfrag(pack + OFF_WR2, 4*w + ks, lane);
      }
      f32x4 ua = {0.f,0.f,0.f,0.f}, ra = {0.f,0.f,0.f,0.f};
#pragma unroll
      for (int ks = 0; ks < 4; ++ks){
        ua = mfma16(ldsA(LDSU, HB_O  + a128[ks]), wu2[ks], ua);
        ra = mfma16(ldsA(LDSU, SGH_O + a128[ks]), wr2[ks], ra);
      }
      f32x4 rr;
#pragma unroll
      for (int i = 0; i < 4; ++i){
        u[i]  = fast_sigmoid(ua[i] + bu2c);
        rr[i] = fast_sigmoid(ra[i] + br2c);
      }
      __syncthreads();   // all waves done reading HB/SGH and HA/SGL stale state
#pragma unroll
      for (int i = 0; i < 4; ++i){
        float ycm = yf[i] * rr[i], ycs = sts[i] * rr[i];
        unsigned short hm = bf16r(ycm);
        LDSU[HA_O  + wrm[i]] = hm;
        LDSU[SGL_O + wrm[i]] = bf16r(ycm - bf16tof(hm));
        unsigned short hs2 = bf16r(ycs);
        LDSU[HA_O  + (wrm[i] ^ 64)] = hs2;
        LDSU[SGL_O + (wrm[i] ^ 64)] = bf16r(ycs - bf16tof(hs2));
      }
    }
    __syncthreads();
    // ---- g4: n first layer (read HA/SGL, write HB) ----
#pragma unroll
    for (int t = 0; t < 2; ++t){
      bf16x8 bn_[4];
#pragma unroll
      for (int ks = 0; ks < 4; ++ks) bn_[ks] = load_bfrag(pack + OFF_WN1, (2*w + t)*4 + ks, lane);
      f32x4 an = {0.f,0.f,0.f,0.f};
#pragma unroll
      for (int ks = 0; ks < 4; ++ks){
        bf16x8 ah = ldsA(LDSU, HA_O  + a128[ks]);
        bf16x8 al = ldsA(LDSU, SGL_O + a128[ks]);
        an = mfma16(al, bn_[ks], an); an = mfma16(ah, bn_[ks], an);
      }
#pragma unroll
      for (int i = 0; i < 4; ++i)
        LDSU[HB_O + (wrA[i] ^ (t << 4))] = bf16r(fast_tanh(an[i] + bn1c[t] + xr[i] * wn1L[t]));
    }
    __syncthreads();
    // ---- g5: n second layer (mean tile w, std tile 4+w) + blend + write st-mean ----
    {
      bf16x8 n2m[4], n2s[4];
#pragma unroll
      for (int ks = 0; ks < 4; ++ks){
        n2m[ks] = load_bfrag(pack + OFF_WN2, 4*w + ks, lane);
        n2s[ks] = load_bfrag(pack + OFF_WN2, 4*(4 + w) + ks, lane);
      }
      f32x4 am = {0.f,0.f,0.f,0.f}, as = {0.f,0.f,0.f,0.f};
#pragma unroll
      for (int ks = 0; ks < 4; ++ks){
        bf16x8 af = ldsA(LDSU, HB_O + a128[ks]);
        am = mfma16(af, n2m[ks], am);
        as = mfma16(af, n2s[ks], as);
      }
#pragma unroll
      for (int i = 0; i < 4; ++i){
        float nm = am[i] + bn2cm, ns_ = as[i] + bn2cs;
        float uu = u[i], m = mk[i];
        stm[i] = m * ((1.f - uu) * nm + uu * yf[i]) + (1.f - m) * yf[i];
        float fs = m * ((1.f - uu) * ns_ + uu * sts[i]) + (1.f - m) * sts[i];
        sts[i] = fabsf(fs);
      }
#pragma unroll
      for (int i = 0; i < 4; ++i) LDSU[ST_O + wr64[i]] = bf16r(stm[i]);
    }
    __syncthreads();
  }

  // ---- store ----
#pragma unroll
  for (int i = 0; i < 4; ++i){
    int r = rowBase + rb + i;
    out[r * 64 + c64] = stm[i];
    out[524288 + r * 64 + c64] = sts[i];
  }
}

extern "C" void kernel_launch(void* const* d_in, const int* in_sizes, int n_in,
                              void* d_out, int out_size, void* d_ws, size_t ws_size,
                              hipStream_t stream)
{
  (void)in_sizes; (void)n_in; (void)out_size; (void)ws_size;
  unsigned short* pack = (unsigned short*)d_ws;
  float2* xmk = (float2*)((char*)d_ws + XMK_OFF);
  float*  dts = (float*)((char*)d_ws + DTS_OFF);
  prep_pack<<<dim3((PREP_TOT + 255) / 256), dim3(256), 0, stream>>>(
      (const float*)d_in[2],  (const float*)d_in[4],  (const float*)d_in[6],
      (const float*)d_in[8],  (const float*)d_in[12], (const float*)d_in[16],
      (const float*)d_in[10], (const float*)d_in[14], (const float*)d_in[18],
      (const float*)d_in[7],  pack);
  prep_xmk<<<dim3(NROW * T_LEN / 256), dim3(256), 0, stream>>>(
      (const float*)d_in[0], (const float*)d_in[1], xmk, dts);
  ode_rnn_main<<<dim3(512), dim3(256), 0, stream>>>(
      (const float*)d_in[3],  (const float*)d_in[5],  (const float*)d_in[7],
      (const float*)d_in[9],  (const float*)d_in[11],
      (const float*)d_in[13], (const float*)d_in[15],
      (const float*)d_in[17], (const float*)d_in[19],
      (const float*)d_in[8],  (const float*)d_in[12], (const float*)d_in[16],
      (const unsigned short*)pack, (const float2*)xmk, (const float*)dts, (float*)d_out);
}

// Round 8
// 2277.951 us; speedup vs baseline: 3.2252x; 3.2252x over previous
//
#include <hip/hip_runtime.h>

typedef __attribute__((ext_vector_type(8))) short bf16x8;
typedef __attribute__((ext_vector_type(4))) float f32x4;

#define T_LEN 256
// pack offsets (short units)
#define OFF_W1   0
#define OFF_W2   8192
#define OFF_W31  24576
#define OFF_W3   40960
#define OFF_WU1  49152
#define OFF_WR1  65536
#define OFF_WN1  81920
#define OFF_WU2  98304
#define OFF_WR2  106496
#define OFF_WN2  114688
#define OFF_B3W1 131072   // f32[128] appended after bf16 packs
#define PREP_TOT 131200

// LDS layout (short units)
#define HA_O   0      // act buffer A [16][128]
#define HB_O   2048   // act buffer B [16][128]; first 1024 doubles as st-mean
#define SGH_O  4096   // [16][128]
#define SGL_O  6144   // [16][128]
#define WS_O   8192   // staged weights = pack[40960..98304), 57344 shorts
#define W3S    8192   // W3  16 blocks
#define WU1S   16384  // Wu1 32 blocks
#define WR1S   32768  // Wr1 32 blocks
#define WN1S   49152  // Wn1 32 blocks (ends 65536)
#define FU_F   32768  // float-index: u gate f32 [16][64] (shorts 65536..67583)
#define FR_F   33792  // float-index: r gate f32 [16][64] (shorts 67584..69631)
#define LDS_SHORTS 69632
#define WS_COPY 7168  // 57344/8 b128 copies

__device__ __forceinline__ unsigned short bf16r(float f){
  unsigned int x = __builtin_bit_cast(unsigned int, f);
  unsigned int r = (x + 0x7FFFu + ((x >> 16) & 1u)) >> 16;
  return (unsigned short)r;
}
__device__ __forceinline__ float bf16tof(unsigned short u){
  unsigned int v = ((unsigned int)u) << 16;
  return __builtin_bit_cast(float, v);
}
__device__ __forceinline__ float fast_tanh(float x){
  float e = __builtin_amdgcn_exp2f(x * 2.885390081777927f);   // exp(2x)
  return 1.0f - 2.0f * __builtin_amdgcn_rcpf(1.0f + e);
}
__device__ __forceinline__ float fast_sigmoid(float x){
  float e = __builtin_amdgcn_exp2f(x * -1.4426950408889634f); // exp(-x)
  return __builtin_amdgcn_rcpf(1.0f + e);
}
__device__ __forceinline__ f32x4 mfma16(bf16x8 a, bf16x8 b, f32x4 c){
  return __builtin_amdgcn_mfma_f32_16x16x32_bf16(a, b, c, 0, 0, 0);
}
__device__ __forceinline__ bf16x8 load_bfrag(const unsigned short* p, int blk, int lane){
  return *reinterpret_cast<const bf16x8*>(p + ((blk << 6) + lane) * 8);
}
__device__ __forceinline__ bf16x8 ldsA(const unsigned short* LDSU, int idx){
  return *reinterpret_cast<const bf16x8*>(LDSU + idx);
}

// Pack weights to bf16 MFMA B-fragment order; compute W31=W3@W1, b3W1=b3@W1.
__global__ void prep_pack(const float* __restrict__ W1, const float* __restrict__ W2,
                          const float* __restrict__ W3, const float* __restrict__ Wu1,
                          const float* __restrict__ Wr1, const float* __restrict__ Wn1,
                          const float* __restrict__ Wu2, const float* __restrict__ Wr2,
                          const float* __restrict__ Wn2, const float* __restrict__ b3,
                          unsigned short* __restrict__ pack)
{
  int e = blockIdx.x * blockDim.x + threadIdx.x;
  if (e >= PREP_TOT) return;
  if (e >= OFF_B3W1){
    int j = e - OFF_B3W1;           // 0..127
    float s = 0.0f;
    for (int mm = 0; mm < 64; ++mm) s += b3[mm] * W1[mm * 128 + j];
    ((float*)(pack + OFF_B3W1))[j] = s;
    return;
  }
  const int offs[11] = {0, 8192, 24576, 40960, 49152, 65536, 81920, 98304, 106496, 114688, 131072};
  const int Ks[10] = {64,128,128,128,128,128,128,128,128,128};
  const int Ns[10] = {128,128,128,64,128,128,128,64,64,128};
  int m = 0;
  while (e >= offs[m + 1]) ++m;
  int el = e - offs[m];
  int j = el & 7, lane = (el >> 3) & 63, blk = el >> 9;
  int ksteps = Ks[m] >> 5;
  int ks = blk % ksteps, nt = blk / ksteps;
  int k = ks * 32 + ((lane >> 4) << 3) + j;
  int n = nt * 16 + (lane & 15);
  float v;
  if (m == 2){ // W31[k][n] = sum_mm W3[k][mm] * W1[mm][n]
    float s = 0.0f;
    for (int mm = 0; mm < 64; ++mm) s += W3[k * 64 + mm] * W1[mm * 128 + n];
    v = s;
  } else {
    const float* srcs[10] = {W1, W2, nullptr, W3, Wu1, Wr1, Wn1, Wu2, Wr2, Wn2};
    v = srcs[m][k * Ns[m] + n];
  }
  pack[e] = bf16r(v);
}

__global__ __launch_bounds__(512, 2) void ode_rnn_main(
  const float* __restrict__ bts, const float* __restrict__ mtr,
  const float* __restrict__ b1, const float* __restrict__ b2, const float* __restrict__ b3,
  const float* __restrict__ bu1, const float* __restrict__ bu2,
  const float* __restrict__ br1, const float* __restrict__ br2,
  const float* __restrict__ bn1, const float* __restrict__ bn2,
  const float* __restrict__ Wu1f, const float* __restrict__ Wr1f, const float* __restrict__ Wn1f,
  const unsigned short* __restrict__ pack, float* __restrict__ out)
{
  __shared__ __align__(16) unsigned short LDSU[LDS_SHORTS];
  float* FUR = (float*)LDSU;
  const int tid = threadIdx.x, w = tid >> 6, lane = tid & 63;
  const int arow = lane & 15, g = lane >> 4, rb = g << 2;
  const int c128 = (w << 4) + arow;        // wave's 128-wide column (== state column)
  const int c64  = ((w & 3) << 4) + arow;  // wave's 64-wide column
  const bool isMean = (w < 4);
  const int rowBase = blockIdx.x * 16;

  // ---- prologue: stage once-per-step weights into LDS (only non-loop d_ws reads) ----
#pragma unroll 2
  for (int i = tid; i < WS_COPY; i += 512)
    *reinterpret_cast<bf16x8*>(LDSU + WS_O + (i << 3)) =
        *reinterpret_cast<const bf16x8*>(pack + OFF_W3 + (i << 3));
  // zero st buffer (HB first 2048 shorts = 512 ull, exactly 512 threads)
  ((unsigned long long*)(LDSU + HB_O))[tid] = 0ULL;

  // precomputed LDS indices (short units)
  int a128[4], wr128[4], wr64[4], furi[4], a64v[2];
#pragma unroll
  for (int ks = 0; ks < 4; ++ks) a128[ks] = arow*128 + ((32*ks + 8*g) ^ (arow << 3));
#pragma unroll
  for (int ks = 0; ks < 2; ++ks) a64v[ks] = arow*64 + ((32*ks + 8*g) ^ ((arow & 7) << 3));
#pragma unroll
  for (int i = 0; i < 4; ++i){
    int r = rb + i;
    wr128[i] = r*128 + (c128 ^ (r << 3));
    wr64[i]  = r*64  + (c64 ^ ((r & 7) << 3));
    furi[i]  = r*64 + c64;
  }
  // per-wave staged-weight bases (short units, + ks<<9 per k-step)
  const int wsb  = ((4*w) << 9) + (lane << 3);
  const int w3b  = W3S  + ((4*(w & 3)) << 9) + (lane << 3);
  const int wu1b = WU1S + wsb;
  const int wr1b = WR1S + wsb;
  const int wn1b = WN1S + wsb;

  // persistent per-wave weight fragments (registers)
  bf16x8 w1f[2], w2f[4], w31f[4], g2wf[4], n2f[4];
#pragma unroll
  for (int ks = 0; ks < 2; ++ks) w1f[ks]  = load_bfrag(pack + OFF_W1,  2*w + ks, lane);
#pragma unroll
  for (int ks = 0; ks < 4; ++ks){
    w2f[ks]  = load_bfrag(pack + OFF_W2,  4*w + ks, lane);
    w31f[ks] = load_bfrag(pack + OFF_W31, 4*w + ks, lane);
    g2wf[ks] = load_bfrag(pack + (isMean ? OFF_WU2 : OFF_WR2), 4*(w & 3) + ks, lane);
    n2f[ks]  = load_bfrag(pack + OFF_WN2, 4*w + ks, lane);
  }

  const float* b3w1p = (const float*)(pack + OFF_B3W1);
  const float b1c = b1[c128], b2c = b2[c128], b3c = b3[c64], b3w1c = b3w1p[c128];
  const float bu1c = bu1[c128], br1c = br1[c128], bn1c = bn1[c128], bn2c = bn2[c128];
  const float g2b = isMean ? bu2[c64] : br2[c64];
  const float wu1L = Wu1f[16384 + c128], wr1L = Wr1f[16384 + c128], wn1L = Wn1f[16384 + c128];

  __syncthreads();   // staging + st-zero visible

  f32x4 st = {0.f,0.f,0.f,0.f};   // w<4: mean state; w>=4: std state
  f32x4 yf = {0.f,0.f,0.f,0.f};   // mean_ode (mean waves)
  f32x4 u  = {0.f,0.f,0.f,0.f};

#pragma unroll 1
  for (int s = 0; s < T_LEN; ++s){
    const int tj = T_LEN - 1 - s;
    const float t1 = bts[2*tj];
    const float t0 = (s == 0) ? 5.0f : bts[2*tj + 2];
    const float hh = (t1 - t0);            // single RK4 step over the interval

    // prefetch x, mask early (d_in, L2-cached); used ~9 phases later
    f32x4 xr, mk;
#pragma unroll
    for (int i = 0; i < 4; ++i){
      int r = rowBase + rb + i;
      xr[i] = bts[(r * T_LEN + tj) * 2 + 1];
      mk[i] = mtr[r * T_LEN + tj];
    }

    f32x4 Hsum, R;

    // ---------------- RK4: one substep, 8 phases ----------------
    // p0: h1 stage1 from st-mean (K=64)
    {
      f32x4 acc = (f32x4){b1c, b1c, b1c, b1c};
      acc = mfma16(ldsA(LDSU, HB_O + a64v[0]), w1f[0], acc);
      acc = mfma16(ldsA(LDSU, HB_O + a64v[1]), w1f[1], acc);
      R = acc;
#pragma unroll
      for (int i = 0; i < 4; ++i) LDSU[HA_O + wr128[i]] = bf16r(fast_tanh(acc[i]));
    }
    __syncthreads();
    // 3x { h2 stage | h1 stage }
#pragma unroll
    for (int hs = 0; hs < 3; ++hs){
      const float wgt = (hs == 0) ? 1.0f : 2.0f;
      const float scn = (hs == 2) ? hh : 0.5f * hh;
      {
        f32x4 acc = (f32x4){b2c, b2c, b2c, b2c};
#pragma unroll
        for (int ks = 0; ks < 4; ++ks)
          acc = mfma16(ldsA(LDSU, HA_O + a128[ks]), w2f[ks], acc);
        f32x4 h;
#pragma unroll
        for (int i = 0; i < 4; ++i) h[i] = fast_tanh(acc[i]);
        if (hs == 0) Hsum = h;
        else {
#pragma unroll
          for (int i = 0; i < 4; ++i) Hsum[i] += wgt * h[i];
        }
#pragma unroll
        for (int i = 0; i < 4; ++i) LDSU[SGH_O + wr128[i]] = bf16r(h[i] * scn);
      }
      __syncthreads();
      {
        const float ac = (hs == 2) ? hh : 0.5f * hh;
        f32x4 acc2;
#pragma unroll
        for (int i = 0; i < 4; ++i) acc2[i] = R[i] + ac * b3w1c;
#pragma unroll
        for (int ks = 0; ks < 4; ++ks)
          acc2 = mfma16(ldsA(LDSU, SGH_O + a128[ks]), w31f[ks], acc2);
#pragma unroll
        for (int i = 0; i < 4; ++i) LDSU[HA_O + wr128[i]] = bf16r(fast_tanh(acc2[i]));
      }
      __syncthreads();
    }
    // p7: h2 stage 4, finalize Gsum hi/lo -> HB/SGH
    {
      f32x4 acc = (f32x4){b2c, b2c, b2c, b2c};
#pragma unroll
      for (int ks = 0; ks < 4; ++ks)
        acc = mfma16(ldsA(LDSU, HA_O + a128[ks]), w2f[ks], acc);
      const float sc6 = hh * (1.0f / 6.0f);
#pragma unroll
      for (int i = 0; i < 4; ++i){
        float h = fast_tanh(acc[i]);
        float gv = (Hsum[i] + h) * sc6;
        unsigned short hi = bf16r(gv);
        LDSU[HB_O  + wr128[i]] = hi;
        LDSU[SGH_O + wr128[i]] = bf16r(gv - bf16tof(hi));
      }
    }
    __syncthreads();
    // Y: recover mean_ode (W3 from LDS stage) + write state hi/lo -> HA/SGL
    if (isMean){
      f32x4 acc = {0.f,0.f,0.f,0.f};
#pragma unroll
      for (int ks = 0; ks < 4; ++ks)
        acc = mfma16(ldsA(LDSU, HB_O  + a128[ks]), ldsA(LDSU, w3b + (ks << 9)), acc);
#pragma unroll
      for (int ks = 0; ks < 4; ++ks)
        acc = mfma16(ldsA(LDSU, SGH_O + a128[ks]), ldsA(LDSU, w3b + (ks << 9)), acc);
#pragma unroll
      for (int i = 0; i < 4; ++i) yf[i] = st[i] + acc[i] + hh * b3c;
#pragma unroll
      for (int i = 0; i < 4; ++i){
        unsigned short hi = bf16r(yf[i]);
        LDSU[HA_O  + wr128[i]] = hi;
        LDSU[SGL_O + wr128[i]] = bf16r(yf[i] - bf16tof(hi));
      }
    } else {
#pragma unroll
      for (int i = 0; i < 4; ++i){
        unsigned short hi = bf16r(st[i]);
        LDSU[HA_O  + wr128[i]] = hi;
        LDSU[SGL_O + wr128[i]] = bf16r(st[i] - bf16tof(hi));
      }
    }
    __syncthreads();
    // g1: u & r first layers (weights from LDS stage; read HA/SGL, write HB/SGH)
    {
      f32x4 au = {0.f,0.f,0.f,0.f}, ar = {0.f,0.f,0.f,0.f};
#pragma unroll
      for (int ks = 0; ks < 4; ++ks){
        bf16x8 ah = ldsA(LDSU, HA_O  + a128[ks]);
        bf16x8 al = ldsA(LDSU, SGL_O + a128[ks]);
        bf16x8 bu = ldsA(LDSU, wu1b + (ks << 9));
        bf16x8 br_ = ldsA(LDSU, wr1b + (ks << 9));
        au = mfma16(al, bu, au);  au = mfma16(ah, bu, au);
        ar = mfma16(al, br_, ar); ar = mfma16(ah, br_, ar);
      }
#pragma unroll
      for (int i = 0; i < 4; ++i){
        au[i] = fast_tanh(au[i] + bu1c + xr[i] * wu1L);
        ar[i] = fast_tanh(ar[i] + br1c + xr[i] * wr1L);
      }
#pragma unroll
      for (int i = 0; i < 4; ++i){
        LDSU[HB_O  + wr128[i]] = bf16r(au[i]);
        LDSU[SGH_O + wr128[i]] = bf16r(ar[i]);
      }
    }
    __syncthreads();
    // g2: second layers from registers (mean->u from HB, std->r from SGH)
    f32x4 rr = {0.f,0.f,0.f,0.f};
    {
      f32x4 acc = {0.f,0.f,0.f,0.f};
      const int srcO = isMean ? HB_O : SGH_O;
#pragma unroll
      for (int ks = 0; ks < 4; ++ks)
        acc = mfma16(ldsA(LDSU, srcO + a128[ks]), g2wf[ks], acc);
      if (isMean){
#pragma unroll
        for (int i = 0; i < 4; ++i){ u[i] = fast_sigmoid(acc[i] + g2b); FUR[FU_F + furi[i]] = u[i]; }
      } else {
#pragma unroll
        for (int i = 0; i < 4; ++i){ rr[i] = fast_sigmoid(acc[i] + g2b); FUR[FR_F + furi[i]] = rr[i]; }
      }
    }
    __syncthreads();
    // g3: gated state yc -> HB(hi)/SGH(lo)
    {
      f32x4 yc;
      if (isMean){
#pragma unroll
        for (int i = 0; i < 4; ++i){ float r_ = FUR[FR_F + furi[i]]; yc[i] = yf[i] * r_; }
      } else {
#pragma unroll
        for (int i = 0; i < 4; ++i){ u[i] = FUR[FU_F + furi[i]]; yc[i] = st[i] * rr[i]; }
      }
#pragma unroll
      for (int i = 0; i < 4; ++i){
        unsigned short hi = bf16r(yc[i]);
        LDSU[HB_O  + wr128[i]] = hi;
        LDSU[SGH_O + wr128[i]] = bf16r(yc[i] - bf16tof(hi));
      }
    }
    __syncthreads();
    // g4: n first layer (weights from LDS stage; read HB/SGH, write HA)
    {
      f32x4 an = {0.f,0.f,0.f,0.f};
#pragma unroll
      for (int ks = 0; ks < 4; ++ks){
        bf16x8 ah = ldsA(LDSU, HB_O  + a128[ks]);
        bf16x8 al = ldsA(LDSU, SGH_O + a128[ks]);
        bf16x8 bn = ldsA(LDSU, wn1b + (ks << 9));
        an = mfma16(al, bn, an); an = mfma16(ah, bn, an);
      }
#pragma unroll
      for (int i = 0; i < 4; ++i) an[i] = fast_tanh(an[i] + bn1c + xr[i] * wn1L);
#pragma unroll
      for (int i = 0; i < 4; ++i) LDSU[HA_O + wr128[i]] = bf16r(an[i]);
    }
    __syncthreads();
    // g5: n second layer from registers + blend + write st-mean -> HB[16][64]
    {
      f32x4 ns = {0.f,0.f,0.f,0.f};
#pragma unroll
      for (int ks = 0; ks < 4; ++ks)
        ns = mfma16(ldsA(LDSU, HA_O + a128[ks]), n2f[ks], ns);
#pragma unroll
      for (int i = 0; i < 4; ++i){
        float nv = ns[i] + bn2c;
        float uu = u[i];
        float base = isMean ? yf[i] : st[i];
        float nm = (1.0f - uu) * nv + uu * base;
        float fs = mk[i] * nm + (1.0f - mk[i]) * base;
        st[i] = isMean ? fs : fabsf(fs);
      }
      if (isMean){
#pragma unroll
        for (int i = 0; i < 4; ++i) LDSU[HB_O + wr64[i]] = bf16r(st[i]);
      }
    }
    __syncthreads();
  }

  // ---------------- store ----------------
#pragma unroll
  for (int i = 0; i < 4; ++i){
    int r = rowBase + rb + i;
    if (isMean) out[r * 64 + c64] = st[i];
    else        out[524288 + r * 64 + c64] = st[i];
  }
}

extern "C" void kernel_launch(void* const* d_in, const int* in_sizes, int n_in,
                              void* d_out, int out_size, void* d_ws, size_t ws_size,
                              hipStream_t stream)
{
  (void)in_sizes; (void)n_in; (void)out_size; (void)ws_size;
  unsigned short* pack = (unsigned short*)d_ws;
  prep_pack<<<dim3((PREP_TOT + 255) / 256), dim3(256), 0, stream>>>(
      (const float*)d_in[2],  (const float*)d_in[4],  (const float*)d_in[6],
      (const float*)d_in[8],  (const float*)d_in[12], (const float*)d_in[16],
      (const float*)d_in[10], (const float*)d_in[14], (const float*)d_in[18],
      (const float*)d_in[7],  pack);
  ode_rnn_main<<<dim3(512), dim3(512), 0, stream>>>(
      (const float*)d_in[0],  (const float*)d_in[1],
      (const float*)d_in[3],  (const float*)d_in[5],  (const float*)d_in[7],
      (const float*)d_in[9],  (const float*)d_in[11],
      (const float*)d_in[13], (const float*)d_in[15],
      (const float*)d_in[17], (const float*)d_in[19],
      (const float*)d_in[8],  (const float*)d_in[12], (const float*)d_in[16],
      (const unsigned short*)pack, (float*)d_out);
}